// Round 4
// baseline (716.591 us; speedup 1.0000x reference)
//
#include <hip/hip_runtime.h>
#include <hip/hip_bf16.h>
#include <cstdint>
#include <cstddef>

#define BATCH 2
#define NNODE 50000
#define NEDGE 150000
#define FDIM 256
#define MTOT (BATCH * NNODE)        // 100000 rows
#define NSEG (2 * BATCH * NNODE)    // 200000 CSR rows
#define SCAN_NB 98                  // ceil(200000 / 2048)

typedef __attribute__((ext_vector_type(8))) __bf16 bf16x8;
typedef __attribute__((ext_vector_type(8))) ushort u16x8;
typedef __attribute__((ext_vector_type(4))) float f32x4;
typedef __attribute__((ext_vector_type(4))) uint32_t u32x4;

typedef const __attribute__((address_space(1))) uint32_t* gptr_t;
typedef __attribute__((address_space(3))) uint32_t* lptr_t;

__device__ __forceinline__ ushort f32_to_bf16_rne(float x) {
    uint32_t u = __builtin_bit_cast(uint32_t, x);
    u = (u + 0x7fffu + ((u >> 16) & 1u)) >> 16;
    return (ushort)u;
}

__device__ __forceinline__ void split2(float x, ushort& h, ushort& l) {
    h = f32_to_bf16_rne(x);
    float hf = __builtin_bit_cast(float, ((uint32_t)h) << 16);
    l = f32_to_bf16_rne(x - hf);
}

// ---------------------------------------------------------------------------
// Prep: build swizzled B LDS-images (unchanged from round 3).
// ---------------------------------------------------------------------------
__global__ __launch_bounds__(256)
void prep_kernel(const float* __restrict__ W1, const float* __restrict__ W2,
                 ushort* __restrict__ i1h, ushort* __restrict__ i1l,
                 ushort* __restrict__ i2h, ushort* __restrict__ i2l) {
    int idx = blockIdx.x * 256 + threadIdx.x;
    if (idx < 24576) {
        int kb = idx >> 10;
        int col = (idx >> 2) & 255;
        int s = idx & 3;
        int cb = col >> 7, c = col & 127;
        int sw = s ^ ((c >> 1) & 3);
        ushort hs[8], ls[8];
#pragma unroll
        for (int j = 0; j < 8; ++j) {
            int k = kb * 32 + sw * 8 + j;
            split2(W1[(size_t)k * 256 + col], hs[j], ls[j]);
        }
        size_t off = ((size_t)(kb * 2 + cb) * 128 + c) * 32 + s * 8;
#pragma unroll
        for (int j = 0; j < 8; ++j) { i1h[off + j] = hs[j]; i1l[off + j] = ls[j]; }
    }
    if (idx < 8192) {
        int kb = idx >> 10;
        int col = (idx >> 2) & 255;
        int s = idx & 3;
        int cb = col >> 7, c = col & 127;
        int sw = s ^ ((c >> 1) & 3);
        ushort hs[8], ls[8];
#pragma unroll
        for (int j = 0; j < 8; ++j) {
            int k = kb * 32 + sw * 8 + j;
            split2(W2[(size_t)k * 256 + col], hs[j], ls[j]);
        }
        size_t off = ((size_t)(kb * 2 + cb) * 128 + c) * 32 + s * 8;
#pragma unroll
        for (int j = 0; j < 8; ++j) { i2h[off + j] = hs[j]; i2l[off + j] = ls[j]; }
    }
}

// ---------------------------------------------------------------------------
// X split: fp32 -> h/l bf16 planes (only launched when ws_size permits).
// ---------------------------------------------------------------------------
__global__ __launch_bounds__(256)
void xsplit_kernel(const float* __restrict__ X,
                   ushort* __restrict__ Xh, ushort* __restrict__ Xl) {
    size_t i = (size_t)blockIdx.x * 256 + threadIdx.x;   // one float4 each
    float4 v = *(const float4*)(X + i * 4);
    ushort h0, l0, h1, l1, h2, l2, h3, l3;
    split2(v.x, h0, l0); split2(v.y, h1, l1);
    split2(v.z, h2, l2); split2(v.w, h3, l3);
    *(ushort4*)(Xh + i * 4) = make_ushort4(h0, h1, h2, h3);
    *(ushort4*)(Xl + i * 4) = make_ushort4(l0, l1, l2, l3);
}

// ---------------------------------------------------------------------------
// CSR build. Row allocations padded to multiples of 4; pad slots are zeroed
// (pidx=0, pw=0) by the host-side memset so gather can run full 4-chunks.
// ---------------------------------------------------------------------------
__global__ __launch_bounds__(256)
void hist_kernel(const int* __restrict__ ri, const int* __restrict__ ro,
                 int* __restrict__ cnt) {
    int j = blockIdx.x * 256 + threadIdx.x;
    if (j >= BATCH * NEDGE) return;
    int b = j / NEDGE;
    atomicAdd(&cnt[(0 * BATCH + b) * NNODE + ri[j]], 1);
    atomicAdd(&cnt[(1 * BATCH + b) * NNODE + ro[j]], 1);
}

__global__ __launch_bounds__(256)
void scan1_kernel(const int* __restrict__ cnt, int* __restrict__ rs,
                  int* __restrict__ bsum) {
    __shared__ int s[256];
    int tid = threadIdx.x;
    int base = blockIdx.x * 2048 + tid * 8;
    int v[8];
    int loc = 0;
#pragma unroll
    for (int j = 0; j < 8; ++j) {
        int idx = base + j;
        int x = (idx < NSEG) ? cnt[idx] : 0;
        x = (x + 3) & ~3;                 // pad each row to multiple of 4
        v[j] = x;
        loc += x;
    }
    s[tid] = loc;
    __syncthreads();
    for (int off = 1; off < 256; off <<= 1) {
        int t = (tid >= off) ? s[tid - off] : 0;
        __syncthreads();
        s[tid] += t;
        __syncthreads();
    }
    int run = (tid == 0) ? 0 : s[tid - 1];
#pragma unroll
    for (int j = 0; j < 8; ++j) {
        int idx = base + j;
        if (idx < NSEG) rs[idx] = run;
        run += v[j];
    }
    if (tid == 255) bsum[blockIdx.x] = s[255];
}

__global__ __launch_bounds__(128)
void scan2_kernel(int* __restrict__ bsum) {
    __shared__ int s[128];
    int tid = threadIdx.x;
    int x = (tid < SCAN_NB) ? bsum[tid] : 0;
    s[tid] = x;
    __syncthreads();
    for (int off = 1; off < 128; off <<= 1) {
        int t = (tid >= off) ? s[tid - off] : 0;
        __syncthreads();
        s[tid] += t;
        __syncthreads();
    }
    int ex = (tid == 0) ? 0 : s[tid - 1];
    if (tid < SCAN_NB) bsum[tid] = ex;
}

__global__ __launch_bounds__(256)
void scan3_kernel(int* __restrict__ rs, int* __restrict__ cur,
                  const int* __restrict__ bsum) {
    int base = blockIdx.x * 2048 + threadIdx.x * 8;
    int off = bsum[blockIdx.x];
#pragma unroll
    for (int j = 0; j < 8; ++j) {
        int idx = base + j;
        if (idx < NSEG) {
            int v = rs[idx] + off;
            rs[idx] = v;
            cur[idx] = v;
        }
    }
}

__global__ __launch_bounds__(256)
void fill_kernel(const int* __restrict__ ri, const int* __restrict__ ro,
                 const float* __restrict__ e, int* __restrict__ cur,
                 int* __restrict__ pidx, float* __restrict__ pw) {
    int j = blockIdx.x * 256 + threadIdx.x;
    if (j >= BATCH * NEDGE) return;
    int b = j / NEDGE;
    int vri = ri[j], vro = ro[j];
    float ew = e[j];
    int p0 = atomicAdd(&cur[(0 * BATCH + b) * NNODE + vri], 1);
    pidx[p0] = vro;
    pw[p0] = ew;
    int p1 = atomicAdd(&cur[(1 * BATCH + b) * NNODE + vro], 1);
    pidx[p1] = vri;
    pw[p1] = ew;
}

// ---------------------------------------------------------------------------
// Gather: one wave per CSR row; 4-edge chunks (padded), 4 X-rows in flight.
// Output written directly as split h/l bf16 planes.
// ---------------------------------------------------------------------------
__global__ __launch_bounds__(256)
void gather_kernel(const float* __restrict__ X, const int* __restrict__ rs,
                   const int* __restrict__ cnt, const int* __restrict__ pidx,
                   const float* __restrict__ pw,
                   ushort* __restrict__ mih, ushort* __restrict__ mil,
                   ushort* __restrict__ moh, ushort* __restrict__ mol) {
    int gid = blockIdx.x * 256 + threadIdx.x;
    int w = gid >> 6;
    int lane = gid & 63;
    if (w >= NSEG) return;
    int t = w / (BATCH * NNODE);
    int r = w - t * (BATCH * NNODE);
    int b = r / NNODE;
    int start = rs[w];
    int c4 = (cnt[w] + 3) & ~3;
    const float* Xb = X + (size_t)b * NNODE * FDIM + lane * 4;
    float4 acc = make_float4(0.f, 0.f, 0.f, 0.f);
    for (int i = 0; i < c4; i += 4) {
        int4 v = *(const int4*)(pidx + start + i);
        float4 wv = *(const float4*)(pw + start + i);
        float4 x0 = *(const float4*)(Xb + (size_t)v.x * FDIM);
        float4 x1 = *(const float4*)(Xb + (size_t)v.y * FDIM);
        float4 x2 = *(const float4*)(Xb + (size_t)v.z * FDIM);
        float4 x3 = *(const float4*)(Xb + (size_t)v.w * FDIM);
        acc.x += wv.x * x0.x + wv.y * x1.x + wv.z * x2.x + wv.w * x3.x;
        acc.y += wv.x * x0.y + wv.y * x1.y + wv.z * x2.y + wv.w * x3.y;
        acc.z += wv.x * x0.z + wv.y * x1.z + wv.z * x2.z + wv.w * x3.z;
        acc.w += wv.x * x0.w + wv.y * x1.w + wv.z * x2.w + wv.w * x3.w;
    }
    ushort h0, l0, h1, l1, h2, l2, h3, l3;
    split2(acc.x, h0, l0); split2(acc.y, h1, l1);
    split2(acc.z, h2, l2); split2(acc.w, h3, l3);
    size_t o = (size_t)r * FDIM + lane * 4;
    ushort* ph = (t == 0 ? mih : moh);
    ushort* pl = (t == 0 ? mil : mol);
    *(ushort4*)(ph + o) = make_ushort4(h0, h1, h2, h3);
    *(ushort4*)(pl + o) = make_ushort4(l0, l1, l2, l3);
}

// ---------------------------------------------------------------------------
// 2-phase pipelined split-bf16 GEMM.  C = tanh(A @ W + bias).
// AMODE 0 (gemm1, NT=24): A-steps 0-7 mi planes, 8-15 mo planes,
//   16-23 X (planes if XPL else fp32 + in-register split). Out packed u32.
// AMODE 1 (gemm2, NT=8): A = hbuf packed u32, unpack in-register. Out fp32.
// Plane A-tiles: LDS [ks][row] 16B slots -> 2-way banks (free), staged with
//   global_load_lds from [row][k] planes (4 ks-slices/row = one 64B sector).
// ---------------------------------------------------------------------------
template<int NT, int AMODE, bool XPL>
__global__ __launch_bounds__(256, 2)
void gemm_kernel(const ushort* __restrict__ Ah0, const ushort* __restrict__ Al0,
                 const ushort* __restrict__ Ah1, const ushort* __restrict__ Al1,
                 const ushort* __restrict__ Axh, const ushort* __restrict__ Axl,
                 const float* __restrict__ Xf,
                 const ushort* __restrict__ Bh_img, const ushort* __restrict__ Bl_img,
                 const float* __restrict__ bias,
                 uint32_t* __restrict__ hout, float* __restrict__ fout) {
    __shared__ char smem[65536];

    int tid = threadIdx.x;
    int lane = tid & 63;
    int w = tid >> 6;
    int wm = w >> 1, wn = w & 1;
    int r0 = blockIdx.x * 128;
    int cb = blockIdx.y;
    int c0 = cb * 128;

    f32x4 acc[4][4];
    f32x4 zero4 = {0.f, 0.f, 0.f, 0.f};
#pragma unroll
    for (int m = 0; m < 4; ++m)
#pragma unroll
        for (int n = 0; n < 4; ++n) acc[m][n] = zero4;

    auto stage = [&](int buf, int t) {
        char* abase = smem + buf * 16384;
        if constexpr (AMODE == 0) {
            if (XPL || t < 16) {
                const ushort *hp, *lp;
                int kb;
                if (t < 8)       { hp = Ah0; lp = Al0; kb = t * 32; }
                else if (t < 16) { hp = Ah1; lp = Al1; kb = (t - 8) * 32; }
                else             { hp = Axh; lp = Axl; kb = (t - 16) * 32; }
#pragma unroll
                for (int i = 0; i < 2; ++i) {
                    int j = w * 2 + i;
                    int ks = j & 3, half = j >> 2;
                    int rowg = r0 + half * 64 + lane;
                    if (rowg > MTOT - 1) rowg = MTOT - 1;
                    size_t go = (size_t)rowg * 512 + (size_t)(kb + ks * 8) * 2;
                    int ld = (ks * 128 + half * 64) * 16;
                    __builtin_amdgcn_global_load_lds((gptr_t)((const char*)hp + go),
                                                     (lptr_t)(abase + ld), 16, 0, 0);
                    __builtin_amdgcn_global_load_lds((gptr_t)((const char*)lp + go),
                                                     (lptr_t)(abase + 8192 + ld), 16, 0, 0);
                }
            } else {
                int kb = (t - 16) * 128;
#pragma unroll
                for (int i = 0; i < 4; ++i) {
                    int inst = w * 4 + i;
                    int row = inst * 8 + (lane >> 3);
                    int rowg = r0 + row;
                    if (rowg > MTOT - 1) rowg = MTOT - 1;
                    int slot = (lane & 7) ^ (row & 7);
                    const char* g = (const char*)Xf + (size_t)rowg * 1024 + kb + slot * 16;
                    __builtin_amdgcn_global_load_lds((gptr_t)g, (lptr_t)(abase + inst * 1024), 16, 0, 0);
                }
            }
        } else {
            int kb = t * 128;
#pragma unroll
            for (int i = 0; i < 4; ++i) {
                int inst = w * 4 + i;
                int row = inst * 8 + (lane >> 3);
                int rowg = r0 + row;
                if (rowg > MTOT - 1) rowg = MTOT - 1;
                int slot = (lane & 7) ^ (row & 7);
                const char* g = (const char*)Ah0 + (size_t)rowg * 1024 + kb + slot * 16;
                __builtin_amdgcn_global_load_lds((gptr_t)g, (lptr_t)(abase + inst * 1024), 16, 0, 0);
            }
        }
        // ---- B: 8KB h + 8KB l from prebuilt swizzled image
        int blk = t * 2 + cb;
        const ushort* sh = Bh_img + (size_t)blk * 4096;
        const ushort* sl = Bl_img + (size_t)blk * 4096;
        char* bhbase = smem + 32768 + buf * 16384;
        char* blbase = bhbase + 8192;
#pragma unroll
        for (int j = 0; j < 2; ++j) {
            int inst = w * 2 + j;
            __builtin_amdgcn_global_load_lds((gptr_t)(sh + inst * 512 + lane * 8),
                                             (lptr_t)(bhbase + inst * 1024), 16, 0, 0);
            __builtin_amdgcn_global_load_lds((gptr_t)(sl + inst * 512 + lane * 8),
                                             (lptr_t)(blbase + inst * 1024), 16, 0, 0);
        }
    };

    stage(0, 0);
    asm volatile("s_waitcnt vmcnt(0)" ::: "memory");
    __builtin_amdgcn_s_barrier();

    int cur = 0;
    for (int t = 0; t < NT; ++t) {
        if (t + 1 < NT) stage(cur ^ 1, t + 1);

        char* abase = smem + cur * 16384;
        char* bhbase = smem + 32768 + cur * 16384;
        char* blbase = bhbase + 8192;

        bf16x8 ah[4], al[4], bh[4], bl[4];
        int ks = lane >> 4;
        if (AMODE == 0 && (XPL || t < 16)) {
#pragma unroll
            for (int m = 0; m < 4; ++m) {
                int rowf = wm * 64 + m * 16 + (lane & 15);
                ah[m] = *(const bf16x8*)(abase + (ks * 128 + rowf) * 16);
                al[m] = *(const bf16x8*)(abase + 8192 + (ks * 128 + rowf) * 16);
            }
        } else {
            int q0 = ks * 2;
#pragma unroll
            for (int m = 0; m < 4; ++m) {
                int row = wm * 64 + m * 16 + (lane & 15);
                const char* rp = abase + row * 128;
                if constexpr (AMODE == 0) {
                    f32x4 lo = *(const f32x4*)(rp + ((q0) ^ (row & 7)) * 16);
                    f32x4 hi = *(const f32x4*)(rp + ((q0 + 1) ^ (row & 7)) * 16);
                    float v[8] = {lo[0], lo[1], lo[2], lo[3], hi[0], hi[1], hi[2], hi[3]};
                    u16x8 hv, lv;
#pragma unroll
                    for (int j = 0; j < 8; ++j) {
                        ushort hh, ll;
                        split2(v[j], hh, ll);
                        hv[j] = hh;
                        lv[j] = ll;
                    }
                    ah[m] = __builtin_bit_cast(bf16x8, hv);
                    al[m] = __builtin_bit_cast(bf16x8, lv);
                } else {
                    u32x4 lo = *(const u32x4*)(rp + ((q0) ^ (row & 7)) * 16);
                    u32x4 hi = *(const u32x4*)(rp + ((q0 + 1) ^ (row & 7)) * 16);
                    u16x8 hv, lv;
#pragma unroll
                    for (int j = 0; j < 4; ++j) {
                        hv[j] = (ushort)lo[j];
                        lv[j] = (ushort)(lo[j] >> 16);
                        hv[j + 4] = (ushort)hi[j];
                        lv[j + 4] = (ushort)(hi[j] >> 16);
                    }
                    ah[m] = __builtin_bit_cast(bf16x8, hv);
                    al[m] = __builtin_bit_cast(bf16x8, lv);
                }
            }
        }
#pragma unroll
        for (int n = 0; n < 4; ++n) {
            int c = wn * 64 + n * 16 + (lane & 15);
            int so = (ks ^ ((c >> 1) & 3)) * 16;
            bh[n] = *(const bf16x8*)(bhbase + c * 64 + so);
            bl[n] = *(const bf16x8*)(blbase + c * 64 + so);
        }
#pragma unroll
        for (int m = 0; m < 4; ++m)
#pragma unroll
            for (int n = 0; n < 4; ++n) {
                acc[m][n] = __builtin_amdgcn_mfma_f32_16x16x32_bf16(ah[m], bh[n], acc[m][n], 0, 0, 0);
                acc[m][n] = __builtin_amdgcn_mfma_f32_16x16x32_bf16(al[m], bh[n], acc[m][n], 0, 0, 0);
                acc[m][n] = __builtin_amdgcn_mfma_f32_16x16x32_bf16(ah[m], bl[n], acc[m][n], 0, 0, 0);
            }

        asm volatile("s_waitcnt vmcnt(0)" ::: "memory");
        __builtin_amdgcn_s_barrier();
        cur ^= 1;
    }

    // ---- epilogue: bias + tanh ----
#pragma unroll
    for (int m = 0; m < 4; ++m) {
        int rbase = r0 + wm * 64 + m * 16 + ((lane >> 4) * 4);
#pragma unroll
        for (int n = 0; n < 4; ++n) {
            int col = c0 + wn * 64 + n * 16 + (lane & 15);
            float bv = bias[col];
#pragma unroll
            for (int q = 0; q < 4; ++q) {
                int row = rbase + q;
                if (row < MTOT) {
                    float tv = tanhf(acc[m][n][q] + bv);
                    if constexpr (AMODE == 0) {
                        ushort h, l;
                        split2(tv, h, l);
                        hout[(size_t)row * 256 + col] = (uint32_t)h | ((uint32_t)l << 16);
                    } else {
                        fout[(size_t)row * 256 + col] = tv;
                    }
                }
            }
        }
    }
}

// ---------------------------------------------------------------------------
extern "C" void kernel_launch(void* const* d_in, const int* in_sizes, int n_in,
                              void* d_out, int out_size, void* d_ws, size_t ws_size,
                              hipStream_t stream) {
    const float* X  = (const float*)d_in[0];
    const float* e  = (const float*)d_in[1];
    const int*   ri = (const int*)d_in[2];
    const int*   ro = (const int*)d_in[3];
    const float* W1 = (const float*)d_in[4];
    const float* b1 = (const float*)d_in[5];
    const float* W2 = (const float*)d_in[6];
    const float* b2 = (const float*)d_in[7];
    float* out = (float*)d_out;

    char* ws = (char*)d_ws;
    const size_t szP = (size_t)MTOT * 256 * 2;           // 51,200,000 B per plane
    ushort* mih = (ushort*)ws;
    ushort* mil = (ushort*)(ws + szP);
    ushort* moh = (ushort*)(ws + 2 * szP);
    ushort* mol = (ushort*)(ws + 3 * szP);
    char*   hreg = ws + 4 * szP;                         // 102,400,000 B hbuf region
    uint32_t* hbuf = (uint32_t*)hreg;
    char*   img = hreg + 2 * szP;
    ushort* i1h = (ushort*)img;                          // 393,216 B
    ushort* i1l = i1h + 196608;
    ushort* i2h = i1l + 196608;                          // 131,072 B
    ushort* i2l = i2h + 65536;
    char*   xw  = img + 1048576;
    ushort* Xh  = (ushort*)xw;
    ushort* Xl  = (ushort*)(xw + szP);
    const size_t NEED_XPL = 4 * szP + 2 * szP + 1048576 + 2 * szP;  // ~410.6 MB
    bool xpl = ws_size >= NEED_XPL;

    // CSR temps inside hbuf region (dead before gemm1 writes hbuf)
    int*   cnt  = (int*)(hreg);                          // 800,000
    int*   rs   = (int*)(hreg + 800000);                 // 800,000
    int*   curp = (int*)(hreg + 1600000);                // 800,000
    int*   bsum = (int*)(hreg + 2400000);                // 4,096
    int*   pidx = (int*)(hreg + 2404096);                // 4,800,000 (1.2M slots)
    float* pw   = (float*)(hreg + 7204096);              // 4,800,000

    // zero cnt + pad-slots of pidx/pw in one shot (12 MB)
    hipMemsetAsync(hreg, 0, 12004096, stream);

    prep_kernel<<<96, 256, 0, stream>>>(W1, W2, i1h, i1l, i2h, i2l);
    if (xpl) xsplit_kernel<<<25000, 256, 0, stream>>>(X, Xh, Xl);

    hist_kernel<<<(BATCH * NEDGE + 255) / 256, 256, 0, stream>>>(ri, ro, cnt);
    scan1_kernel<<<SCAN_NB, 256, 0, stream>>>(cnt, rs, bsum);
    scan2_kernel<<<1, 128, 0, stream>>>(bsum);
    scan3_kernel<<<SCAN_NB, 256, 0, stream>>>(rs, curp, bsum);
    fill_kernel<<<(BATCH * NEDGE + 255) / 256, 256, 0, stream>>>(ri, ro, e, curp, pidx, pw);

    gather_kernel<<<NSEG / 4, 256, 0, stream>>>(X, rs, cnt, pidx, pw, mih, mil, moh, mol);

    dim3 grid1((MTOT + 127) / 128, 2);
    if (xpl) {
        gemm_kernel<24, 0, true><<<grid1, 256, 0, stream>>>(
            mih, mil, moh, mol, Xh, Xl, X, i1h, i1l, b1, hbuf, nullptr);
    } else {
        gemm_kernel<24, 0, false><<<grid1, 256, 0, stream>>>(
            mih, mil, moh, mol, nullptr, nullptr, X, i1h, i1l, b1, hbuf, nullptr);
    }

    gemm_kernel<8, 1, false><<<grid1, 256, 0, stream>>>(
        (const ushort*)hbuf, nullptr, nullptr, nullptr, nullptr, nullptr, nullptr,
        i2h, i2l, b2, nullptr, out);
}